// Round 17
// baseline (258.158 us; speedup 1.0000x reference)
//
#include <hip/hip_runtime.h>
#include <math.h>

typedef __bf16 bf16_t;
typedef __attribute__((ext_vector_type(8))) __bf16 bf16x8;
typedef __attribute__((ext_vector_type(4))) __bf16 bf16x4;
typedef __attribute__((ext_vector_type(4))) float f32x4;
typedef __attribute__((ext_vector_type(16))) float f32x16;
typedef __attribute__((ext_vector_type(4))) unsigned int u32x4;

#define T_LEN 4096
#define C_DIM 1024
#define NH 16
#define HD 64

__device__ __forceinline__ void gload_lds16(const void* g, void* l) {
    __builtin_amdgcn_global_load_lds(
        (__attribute__((address_space(1))) void*)(g),
        (__attribute__((address_space(3))) void*)(l), 16, 0, 0);
}

__device__ __forceinline__ f32x4 mfma16(bf16x8 a, bf16x8 b, f32x4 c) {
    return __builtin_amdgcn_mfma_f32_16x16x32_bf16(a, b, c, 0, 0, 0);
}

__device__ __forceinline__ f32x16 mfma32(bf16x8 a, bf16x8 b, f32x16 c) {
    return __builtin_amdgcn_mfma_f32_32x32x16_bf16(a, b, c, 0, 0, 0);
}

__device__ __forceinline__ float gelu_exact(float v) {
    return 0.5f * v * (1.0f + erff(v * 0.7071067811865476f));
}

// T12: build two PV B-fragments from 16 P values held in C/D layout.
__device__ __forceinline__ void make_frags2(const f32x16 s, bf16x8& fx, bf16x8& fy) {
    unsigned a0, a1, b0, b1;
    asm("v_cvt_pk_bf16_f32 %0, %1, %2" : "=v"(a0) : "v"(s[0]), "v"(s[1]));
    asm("v_cvt_pk_bf16_f32 %0, %1, %2" : "=v"(a1) : "v"(s[2]), "v"(s[3]));
    asm("v_cvt_pk_bf16_f32 %0, %1, %2" : "=v"(b0) : "v"(s[4]), "v"(s[5]));
    asm("v_cvt_pk_bf16_f32 %0, %1, %2" : "=v"(b1) : "v"(s[6]), "v"(s[7]));
    asm("v_permlane32_swap_b32 %0, %1" : "+v"(a0), "+v"(b0));
    asm("v_permlane32_swap_b32 %0, %1" : "+v"(a1), "+v"(b1));
    u32x4 wa = {a0, a1, b0, b1};
    fx = __builtin_bit_cast(bf16x8, wa);
    unsigned c0, c1, d0, d1;
    asm("v_cvt_pk_bf16_f32 %0, %1, %2" : "=v"(c0) : "v"(s[8]), "v"(s[9]));
    asm("v_cvt_pk_bf16_f32 %0, %1, %2" : "=v"(c1) : "v"(s[10]), "v"(s[11]));
    asm("v_cvt_pk_bf16_f32 %0, %1, %2" : "=v"(d0) : "v"(s[12]), "v"(s[13]));
    asm("v_cvt_pk_bf16_f32 %0, %1, %2" : "=v"(d1) : "v"(s[14]), "v"(s[15]));
    asm("v_permlane32_swap_b32 %0, %1" : "+v"(c0), "+v"(d0));
    asm("v_permlane32_swap_b32 %0, %1" : "+v"(c1), "+v"(d1));
    u32x4 wb = {c0, c1, d0, d1};
    fy = __builtin_bit_cast(bf16x8, wb);
}

// ---------------- merged weight transpose+convert (all 4 weights, 1 launch)
__global__ __launch_bounds__(256) void transpose_all(
    const float* __restrict__ wqkv, const float* __restrict__ wo,
    const float* __restrict__ w1, const float* __restrict__ w2,
    bf16_t* __restrict__ oqkv, bf16_t* __restrict__ owo,
    bf16_t* __restrict__ ow1, bf16_t* __restrict__ ow2)
{
    __shared__ float tile[32][33];
    int s = blockIdx.x;
    const float* in; bf16_t* out; int R, C, NBX;
    if (s < 3072)      {            in = wqkv; out = oqkv; R = 1024; C = 3072; NBX = 96; }
    else if (s < 4096) { s -= 3072; in = wo;   out = owo;  R = 1024; C = 1024; NBX = 32; }
    else if (s < 8192) { s -= 4096; in = w1;   out = ow1;  R = 1024; C = 4096; NBX = 128; }
    else               { s -= 8192; in = w2;   out = ow2;  R = 4096; C = 1024; NBX = 32; }
    const int tx = threadIdx.x, ty = threadIdx.y;
    const int c0 = (s % NBX) * 32, r0 = (s / NBX) * 32;
#pragma unroll
    for (int j = 0; j < 4; ++j)
        tile[ty + j * 8][tx] = in[(size_t)(r0 + ty + j * 8) * C + c0 + tx];
    __syncthreads();
#pragma unroll
    for (int j = 0; j < 4; ++j)
        out[(size_t)(c0 + ty + j * 8) * R + r0 + tx] = (bf16_t)tile[tx][ty + j * 8];
}

// ---------------- LayerNorm fp32 -> bf16
__global__ __launch_bounds__(256) void ln_bf16(
    const float* __restrict__ x, const float* __restrict__ gam,
    const float* __restrict__ bet, bf16_t* __restrict__ out)
{
    const int row = blockIdx.x, t = threadIdx.x;
    const float4 v = *(const float4*)(x + (size_t)row * 1024 + t * 4);
    float s1 = v.x + v.y + v.z + v.w;
    float s2 = v.x * v.x + v.y * v.y + v.z * v.z + v.w * v.w;
#pragma unroll
    for (int m = 1; m < 64; m <<= 1) {
        s1 += __shfl_xor(s1, m);
        s2 += __shfl_xor(s2, m);
    }
    __shared__ float red[8];
    if ((t & 63) == 0) { red[(t >> 6) * 2] = s1; red[(t >> 6) * 2 + 1] = s2; }
    __syncthreads();
    s1 = red[0] + red[2] + red[4] + red[6];
    s2 = red[1] + red[3] + red[5] + red[7];
    const float mu = s1 * (1.0f / 1024.0f);
    const float inv = rsqrtf(s2 * (1.0f / 1024.0f) - mu * mu + 1e-5f);
    const float4 gg = *(const float4*)(gam + t * 4);
    const float4 bb = *(const float4*)(bet + t * 4);
    bf16x4 o;
    o[0] = (bf16_t)((v.x - mu) * inv * gg.x + bb.x);
    o[1] = (bf16_t)((v.y - mu) * inv * gg.y + bb.y);
    o[2] = (bf16_t)((v.z - mu) * inv * gg.z + bb.z);
    o[3] = (bf16_t)((v.w - mu) * inv * gg.w + bb.w);
    *(bf16x4*)(out + (size_t)row * 1024 + t * 4) = o;
}

// ---------------- IN-BLOCK split-K 128x128 GEMM (512 thr = 2 groups of 4 waves)
// Group g accumulates K in [g*Khalf, (g+1)*Khalf) with its own 64 KB 4-deep
// LDS ring; workgroup barriers align both groups 1:1 (identical loops,
// disjoint LDS). Epilogue: group 1 dumps acc into dead ring LDS, group 0
// adds + bias + residual -> fp32 out. Used for Wo (Khalf=512, Kstr=1024)
// and W2 (Khalf=2048, Kstr=4096).
__global__ __launch_bounds__(512, 1) void gemm_w2(
    const bf16_t* __restrict__ A, const bf16_t* __restrict__ Bt,
    const float* __restrict__ bias, const float* __restrict__ res,
    float* __restrict__ out, int M, int N, int Khalf, int Kstr)
{
    __shared__ alignas(1024) char smem[131072];
    bf16_t* ring = (bf16_t*)smem;
    const int t = threadIdx.x;
    const int grp = t >> 8, tl = t & 255;
    const int lane = tl & 63, w = tl >> 6;
    const int wr = w >> 1, wc = w & 1;
    const int g = lane >> 4, ci = lane & 15;

    const int NB = gridDim.x, MB = gridDim.y;
    const int flat = blockIdx.x + NB * blockIdx.y;
    const int xcd = flat & 7, slot = flat >> 3;
    const int by = xcd * (MB >> 3) + slot / NB;
    const int bx = slot % NB;
    const int m0 = by * 128, n0 = bx * 128;

    const bf16_t* Ag = A + (size_t)grp * Khalf;
    const bf16_t* Bg = Bt + (size_t)grp * Khalf;

    f32x4 acc[4][4];
#pragma unroll
    for (int i = 0; i < 4; ++i)
#pragma unroll
        for (int j = 0; j < 4; ++j)
#pragma unroll
            for (int k = 0; k < 4; ++k) acc[i][j][k] = 0.0f;

    const int r0 = tl >> 2;
    const int cc = (tl & 3) * 8;
    const int nkt = Khalf >> 5;

    auto stage = [&](int kt) {
        const int b = kt & 3;
        const int kk = kt * 32;
        bf16_t* base = ring + grp * 32768 + b * 8192;   // A at base, B at +4096
        char* aB = (char*)base + w * 1024;
        char* bB = (char*)(base + 4096) + w * 1024;
        gload_lds16(Ag + (size_t)(m0 + r0) * Kstr + kk + cc, aB);
        gload_lds16(Ag + (size_t)(m0 + r0 + 64) * Kstr + kk + cc, aB + 4096);
        gload_lds16(Bg + (size_t)(n0 + r0) * Kstr + kk + cc, bB);
        gload_lds16(Bg + (size_t)(n0 + r0 + 64) * Kstr + kk + cc, bB + 4096);
    };

    stage(0);
    stage(1);
    for (int kt = 0; kt < nkt; ++kt) {
        if (kt + 2 < nkt) {
            stage(kt + 2);
            asm volatile("s_waitcnt vmcnt(8)" ::: "memory");
        } else if (kt + 1 < nkt) {
            asm volatile("s_waitcnt vmcnt(4)" ::: "memory");
        } else {
            asm volatile("s_waitcnt vmcnt(0)" ::: "memory");
        }
        __builtin_amdgcn_s_barrier();
        __builtin_amdgcn_sched_barrier(0);
        const bf16_t* base = ring + grp * 32768 + (kt & 3) * 8192;
        const bf16_t* ap = base + (wr * 64 + ci) * 32 + g * 8;
        const bf16_t* bp = base + 4096 + (wc * 64 + ci) * 32 + g * 8;
        bf16x8 af[4], bf[4];
#pragma unroll
        for (int mt = 0; mt < 4; ++mt) af[mt] = *(const bf16x8*)(ap + mt * 16 * 32);
#pragma unroll
        for (int nt = 0; nt < 4; ++nt) bf[nt] = *(const bf16x8*)(bp + nt * 16 * 32);
        __builtin_amdgcn_s_setprio(1);
#pragma unroll
        for (int mt = 0; mt < 4; ++mt)
#pragma unroll
            for (int nt = 0; nt < 4; ++nt)
                acc[mt][nt] = mfma16(af[mt], bf[nt], acc[mt][nt]);
        __builtin_amdgcn_s_setprio(0);
    }

    // cross-group reduction through (now-dead) ring LDS
    __syncthreads();
    float* ex = (float*)smem;
    if (grp == 1) {
#pragma unroll
        for (int mt = 0; mt < 4; ++mt)
#pragma unroll
            for (int nt = 0; nt < 4; ++nt)
                *(f32x4*)(ex + tl * 68 + (mt * 4 + nt) * 4) = acc[mt][nt];
    }
    __syncthreads();
    if (grp == 0) {
#pragma unroll
        for (int nt = 0; nt < 4; ++nt) {
            const int col = n0 + wc * 64 + nt * 16 + ci;
            const float bv = bias[col];
#pragma unroll
            for (int mt = 0; mt < 4; ++mt) {
                const int row = m0 + wr * 64 + mt * 16 + g * 4;
                const f32x4 p1 = *(const f32x4*)(ex + tl * 68 + (mt * 4 + nt) * 4);
#pragma unroll
                for (int r = 0; r < 4; ++r) {
                    out[(size_t)(row + r) * N + col] =
                        acc[mt][nt][r] + p1[r] + bv +
                        res[(size_t)(row + r) * N + col];
                }
            }
        }
    }
}

// ---------------- 256x256 8-phase GEMM (m201: T2+T3+T4+T5) + T1 XCD swizzle
// EPI: 0 = bf16 out, 1 = gelu->bf16,
//      2 = qkv mode: cols <1024 (Q) scaled by C1; K plain; V transposed out.
template <int EPI>
__global__ __launch_bounds__(512, 2) void gemm256(
    const bf16_t* __restrict__ A, const bf16_t* __restrict__ Bt,
    const float* __restrict__ bias, bf16_t* __restrict__ outb,
    bf16_t* __restrict__ vtout, int M, int N, int K)
{
    __shared__ alignas(1024) bf16_t lds[2][2][256 * 64];
    const int t = threadIdx.x, lane = t & 63, w = t >> 6;
    const int g = lane >> 4, ci = lane & 15;
    const int wr = w >> 2, wc = w & 3;
    const int NB = gridDim.x;
    const int nwg = NB * gridDim.y;
    const int flat = blockIdx.x + NB * blockIdx.y;
    const int rix = (flat & 7) * (nwg >> 3) + (flat >> 3);
    const int m0 = (rix / NB) * 256, n0 = (rix % NB) * 256;
    const int NKT = K >> 6;

    f32x4 acc[8][4];
#pragma unroll
    for (int i = 0; i < 8; ++i)
#pragma unroll
        for (int j = 0; j < 4; ++j)
#pragma unroll
            for (int k2 = 0; k2 < 4; ++k2) acc[i][j][k2] = 0.0f;

    const int sw0 = (g ^ (ci & 7)) * 8;
    const int sw1 = ((4 + g) ^ (ci & 7)) * 8;

    auto stage = [&](int h, int ktile, int b) {
#pragma unroll
        for (int i = 0; i < 2; ++i) {
            const int idx = i * 512 + t;
            const int r = idx >> 3;
            const int c = (t & 7) ^ (r & 7);
            const bf16_t* src = ((h < 2) ? A : Bt)
                + (size_t)(((h < 2) ? m0 : n0) + (h & 1) * 128 + r) * K
                + ktile * 64 + c * 8;
            bf16_t* dst = &lds[b][h >> 1][(h & 1) * 8192] + (i * 512 + w * 64) * 8;
            gload_lds16(src, dst);
        }
    };

    bf16x8 a[4][2], b2[2][2][2];

    stage(0, 0, 0); stage(3, 0, 0); stage(1, 0, 0); stage(2, 0, 0);
    if (NKT > 1) { stage(0, 1, 1); stage(3, 1, 1); stage(1, 1, 1); }
    asm volatile("s_waitcnt vmcnt(6)" ::: "memory");
    __builtin_amdgcn_s_barrier();

    for (int kt = 0; kt < NKT; ++kt) {
        const int cur = kt & 1;
        const bf16_t* Ab = &lds[cur][0][0];
        const bf16_t* Bb = &lds[cur][1][0];

#pragma unroll
        for (int mi = 0; mi < 4; ++mi) {
            const bf16_t* ap = Ab + (wr * 64 + mi * 16 + ci) * 64;
            a[mi][0] = *(const bf16x8*)(ap + sw0);
            a[mi][1] = *(const bf16x8*)(ap + sw1);
        }
#pragma unroll
        for (int ni = 0; ni < 2; ++ni) {
            const bf16_t* bp = Bb + (wc * 32 + ni * 16 + ci) * 64;
            b2[0][ni][0] = *(const bf16x8*)(bp + sw0);
            b2[0][ni][1] = *(const bf16x8*)(bp + sw1);
        }
        if (kt + 1 < NKT) stage(2, kt + 1, cur ^ 1);
        __builtin_amdgcn_s_barrier();
        asm volatile("s_waitcnt lgkmcnt(0)" ::: "memory");
        __builtin_amdgcn_sched_barrier(0);
        __builtin_amdgcn_s_setprio(1);
#pragma unroll
        for (int mi = 0; mi < 4; ++mi)
#pragma unroll
            for (int ni = 0; ni < 2; ++ni) {
                acc[mi][ni] = mfma16(a[mi][0], b2[0][ni][0], acc[mi][ni]);
                acc[mi][ni] = mfma16(a[mi][1], b2[0][ni][1], acc[mi][ni]);
            }
        __builtin_amdgcn_s_setprio(0);
        __builtin_amdgcn_s_barrier();

#pragma unroll
        for (int ni = 0; ni < 2; ++ni) {
            const bf16_t* bp = Bb + (128 + wc * 32 + ni * 16 + ci) * 64;
            b2[1][ni][0] = *(const bf16x8*)(bp + sw0);
            b2[1][ni][1] = *(const bf16x8*)(bp + sw1);
        }
        if (kt + 2 < NKT) stage(0, kt + 2, cur);
        __builtin_amdgcn_s_barrier();
        asm volatile("s_waitcnt lgkmcnt(0)" ::: "memory");
        __builtin_amdgcn_sched_barrier(0);
        __builtin_amdgcn_s_setprio(1);
#pragma unroll
        for (int mi = 0; mi < 4; ++mi)
#pragma unroll
            for (int ni = 0; ni < 2; ++ni) {
                acc[mi][2 + ni] = mfma16(a[mi][0], b2[1][ni][0], acc[mi][2 + ni]);
                acc[mi][2 + ni] = mfma16(a[mi][1], b2[1][ni][1], acc[mi][2 + ni]);
            }
        __builtin_amdgcn_s_setprio(0);
        __builtin_amdgcn_s_barrier();

#pragma unroll
        for (int mi = 0; mi < 4; ++mi) {
            const bf16_t* ap = Ab + (128 + wr * 64 + mi * 16 + ci) * 64;
            a[mi][0] = *(const bf16x8*)(ap + sw0);
            a[mi][1] = *(const bf16x8*)(ap + sw1);
        }
        if (kt + 2 < NKT) stage(3, kt + 2, cur);
        __builtin_amdgcn_s_barrier();
        asm volatile("s_waitcnt lgkmcnt(0)" ::: "memory");
        __builtin_amdgcn_sched_barrier(0);
        __builtin_amdgcn_s_setprio(1);
#pragma unroll
        for (int mi = 0; mi < 4; ++mi)
#pragma unroll
            for (int ni = 0; ni < 2; ++ni) {
                acc[4 + mi][2 + ni] = mfma16(a[mi][0], b2[1][ni][0], acc[4 + mi][2 + ni]);
                acc[4 + mi][2 + ni] = mfma16(a[mi][1], b2[1][ni][1], acc[4 + mi][2 + ni]);
            }
        __builtin_amdgcn_s_setprio(0);
        __builtin_amdgcn_s_barrier();

        if (kt + 2 < NKT) stage(1, kt + 2, cur);
        __builtin_amdgcn_s_barrier();
        __builtin_amdgcn_s_setprio(1);
#pragma unroll
        for (int mi = 0; mi < 4; ++mi)
#pragma unroll
            for (int ni = 0; ni < 2; ++ni) {
                acc[4 + mi][ni] = mfma16(a[mi][0], b2[0][ni][0], acc[4 + mi][ni]);
                acc[4 + mi][ni] = mfma16(a[mi][1], b2[0][ni][1], acc[4 + mi][ni]);
            }
        __builtin_amdgcn_s_setprio(0);
        if (kt + 2 < NKT) asm volatile("s_waitcnt vmcnt(6)" ::: "memory");
        else              asm volatile("s_waitcnt vmcnt(0)" ::: "memory");
        __builtin_amdgcn_s_barrier();
    }

    const float QSC = 0.125f * 1.4426950408889634f;  // C1 folded into Q
#pragma unroll
    for (int mrep = 0; mrep < 8; ++mrep) {
        const int row = m0 + (mrep >> 2) * 128 + wr * 64 + (mrep & 3) * 16 + g * 4;
#pragma unroll
        for (int nrep = 0; nrep < 4; ++nrep) {
            const int col = n0 + (nrep >> 1) * 128 + wc * 32 + (nrep & 1) * 16 + ci;
            const float bv = bias[col];
            if (EPI == 2 && col >= 2048) {
                const int cv = col - 2048;
                bf16x4 o4;
#pragma unroll
                for (int jr = 0; jr < 4; ++jr)
                    o4[jr] = (bf16_t)(acc[mrep][nrep][jr] + bv);
                *(bf16x4*)(vtout + (size_t)(cv >> 6) * 262144
                           + (size_t)(cv & 63) * 4096 + row) = o4;
            } else {
                const float sc = (EPI == 2 && col < 1024) ? QSC : 1.0f;
#pragma unroll
                for (int jr = 0; jr < 4; ++jr) {
                    float v = acc[mrep][nrep][jr] + bv;
                    if constexpr (EPI == 1) v = gelu_exact(v);
                    if (EPI == 2) v *= sc;
                    outb[(size_t)(row + jr) * N + col] = (bf16_t)v;
                }
            }
        }
    }
}

// ---------------- causal flash attention, 4-way split-KV, 256-row q-blocks
// 8 warps x 32 q = 256 q-rows share each KV tile: staging bytes/instructions
// per unit work halve, prefetch window doubles (~2 tiles of compute), KV
// HBM fetch halves. LDS stays 32 KB (512 thr -> 2 resident blocks x 8 waves
// = 16 waves/CU, same TLP as the 4-warp form). qt = 15-(y>>2) (LPT), chunk =
// y&3 covers [chunk*(qt+1), (chunk+1)*(qt+1)) — exactly balanced, never
// empty. wDiag = 4qt + (w>>1) (verified even/odd w). Q pre-scaled by C1;
// p = exp2(s) raw; shared scale cancels in O/l. l via MFMA row-sum.
__global__ __launch_bounds__(512, 2) void attn_fwd(
    const bf16_t* __restrict__ qkv, const bf16_t* __restrict__ vt,
    bf16_t* __restrict__ opart, float* __restrict__ lbuf)
{
    __shared__ alignas(1024) bf16_t Klds[2][64 * 64];
    __shared__ alignas(1024) bf16_t Vlds[2][64 * 64];   // V^T tile [d][kpos]
    const int t = threadIdx.x, lane = t & 63, w = t >> 6;
    const int hi = lane >> 5, li = lane & 31;
    const int lq = li >> 2;
    const int h = blockIdx.x;
    const int y = blockIdx.y;
    const int qt = 15 - (y >> 2);                        // LPT: big tiles first
    const int chunk = y & 3;
    const int q0 = qt * 256;
    const int qrow = q0 + w * 32 + li;
    const int wDiag = 4 * qt + (w >> 1);
    const int ktA = chunk * (qt + 1);
    const int ktB = ktA + qt + 1;

    bf16x8 qf[4];
#pragma unroll
    for (int ks = 0; ks < 4; ++ks)
        qf[ks] = *(const bf16x8*)(qkv + (size_t)qrow * 3072 + h * 64 + ks * 16 + hi * 8);
    bf16x8 ones8;
#pragma unroll
    for (int j = 0; j < 8; ++j) ones8[j] = (bf16_t)1.0f;

    f32x16 oacc[2], lacc;
#pragma unroll
    for (int r = 0; r < 16; ++r) { oacc[0][r] = 0.0f; oacc[1][r] = 0.0f; lacc[r] = 0.0f; }

    const int sr = t >> 3;                               // staging row 0..63
    const int sx = ((t & 7) ^ ((sr >> 2) & 7)) * 8;      // pre-swizzled chunk

    auto stageKV = [&](int kt, int b) {
        gload_lds16(qkv + (size_t)(kt * 64 + sr) * 3072 + 1024 + h * 64 + sx,
                    (char*)&Klds[b][0] + (size_t)t * 16);
        gload_lds16(vt + (size_t)h * 262144 + (size_t)sr * 4096 + kt * 64 + sx,
                    (char*)&Vlds[b][0] + (size_t)t * 16);
    };

    stageKV(ktA, 0);
    for (int kt = ktA; kt < ktB; ++kt) {
        const int cur = (kt - ktA) & 1;
        asm volatile("s_waitcnt vmcnt(0)" ::: "memory");
        __syncthreads();
        if (kt + 1 < ktB) stageKV(kt + 1, cur ^ 1);

        if (kt <= wDiag) {
            const bf16_t* Kb = &Klds[cur][0];
            const bf16_t* Vb = &Vlds[cur][0];
            f32x16 s0, s1;
#pragma unroll
            for (int r = 0; r < 16; ++r) { s0[r] = 0.0f; s1[r] = 0.0f; }

            __builtin_amdgcn_s_setprio(1);
#pragma unroll
            for (int ks = 0; ks < 4; ++ks) {
                const int cs = ((ks * 2 + hi) ^ lq) * 8;
                s0 = mfma32(*(const bf16x8*)(Kb + li * 64 + cs), qf[ks], s0);
                s1 = mfma32(*(const bf16x8*)(Kb + (32 + li) * 64 + cs), qf[ks], s1);
            }
            __builtin_amdgcn_s_setprio(0);

            bf16x8 vf[4][2];
#pragma unroll
            for (int ks = 0; ks < 4; ++ks) {
                const int cs = ((ks * 2 + hi) ^ lq) * 8;
                vf[ks][0] = *(const bf16x8*)(Vb + li * 64 + cs);
                vf[ks][1] = *(const bf16x8*)(Vb + (32 + li) * 64 + cs);
            }

            if (kt == wDiag) {
                const int kb0 = kt * 64 + 4 * hi;
#pragma unroll
                for (int r = 0; r < 16; ++r) {
                    const int kp0 = kb0 + (r & 3) + 8 * (r >> 2);
                    if (kp0 > qrow) s0[r] = -1e30f;
                    if (kp0 + 32 > qrow) s1[r] = -1e30f;
                }
            }
#pragma unroll
            for (int r = 0; r < 16; ++r) {
                s0[r] = exp2f(s0[r]);
                s1[r] = exp2f(s1[r]);
            }

            bf16x8 pf[4];
            make_frags2(s0, pf[0], pf[1]);
            make_frags2(s1, pf[2], pf[3]);

            __builtin_amdgcn_s_setprio(1);
#pragma unroll
            for (int ks = 0; ks < 4; ++ks) {
                oacc[0] = mfma32(vf[ks][0], pf[ks], oacc[0]);
                oacc[1] = mfma32(vf[ks][1], pf[ks], oacc[1]);
                lacc    = mfma32(ones8,     pf[ks], lacc);
            }
            __builtin_amdgcn_s_setprio(0);
        }
        __syncthreads();
    }

    bf16_t* op = opart + ((size_t)chunk * T_LEN + qrow) * 1024 + h * 64 + hi * 4;
#pragma unroll
    for (int dblk = 0; dblk < 2; ++dblk)
#pragma unroll
        for (int gi = 0; gi < 4; ++gi) {
            bf16x4 o4;
#pragma unroll
            for (int j = 0; j < 4; ++j) o4[j] = (bf16_t)oacc[dblk][gi * 4 + j];
            *(bf16x4*)(op + dblk * 32 + gi * 8) = o4;
        }
    if (hi == 0)
        lbuf[((size_t)chunk * T_LEN + qrow) * NH + h] = lacc[0];
}

// ---------------- 4-way split-KV combine (shared scale cancels in O/l)
__global__ __launch_bounds__(256) void attn_combine(
    const bf16_t* __restrict__ opart, const float* __restrict__ lbuf,
    bf16_t* __restrict__ out)
{
    const int row = blockIdx.x, t = threadIdx.x;
    const int c = t * 4, h = c >> 6;
    float l = 0.0f;
#pragma unroll
    for (int k = 0; k < 4; ++k)
        l += lbuf[((size_t)k * T_LEN + row) * NH + h];
    const float inv = 1.0f / l;
    float acc4[4] = {0.f, 0.f, 0.f, 0.f};
#pragma unroll
    for (int k = 0; k < 4; ++k) {
        const bf16x4 o = *(const bf16x4*)(opart + ((size_t)k * T_LEN + row) * 1024 + c);
#pragma unroll
        for (int j = 0; j < 4; ++j) acc4[j] += (float)o[j];
    }
    bf16x4 o;
#pragma unroll
    for (int j = 0; j < 4; ++j) o[j] = (bf16_t)(acc4[j] * inv);
    *(bf16x4*)(out + (size_t)row * 1024 + c) = o;
}

extern "C" void kernel_launch(void* const* d_in, const int* in_sizes, int n_in,
                              void* d_out, int out_size, void* d_ws, size_t ws_size,
                              hipStream_t stream)
{
    const float* x    = (const float*)d_in[0];
    const float* ln1g = (const float*)d_in[1];
    const float* ln1b = (const float*)d_in[2];
    const float* Wqkv = (const float*)d_in[3];
    const float* bqkv = (const float*)d_in[4];
    const float* Wo   = (const float*)d_in[5];
    const float* bo   = (const float*)d_in[6];
    const float* ln2g = (const float*)d_in[7];
    const float* ln2b = (const float*)d_in[8];
    const float* W1   = (const float*)d_in[9];
    const float* b1   = (const float*)d_in[10];
    const float* W2   = (const float*)d_in[11];
    const float* b2   = (const float*)d_in[12];
    float* outp = (float*)d_out;

    char* p = (char*)d_ws;
    bf16_t* WqkvT = (bf16_t*)p; p += (size_t)3072 * 1024 * 2;
    bf16_t* WoT   = (bf16_t*)p; p += (size_t)1024 * 1024 * 2;
    bf16_t* W1T   = (bf16_t*)p; p += (size_t)4096 * 1024 * 2;
    bf16_t* W2T   = (bf16_t*)p; p += (size_t)1024 * 4096 * 2;
    bf16_t* xn    = (bf16_t*)p; p += (size_t)4096 * 1024 * 2;
    bf16_t* qkv   = (bf16_t*)p; p += (size_t)4096 * 3072 * 2;
    bf16_t* vtb   = (bf16_t*)p; p += (size_t)16 * 64 * 4096 * 2;
    bf16_t* attnb = (bf16_t*)p; p += (size_t)4096 * 1024 * 2;
    float*  x2    = (float*)p;  p += (size_t)4096 * 1024 * 4;
    bf16_t* hb    = (bf16_t*)p; p += (size_t)4096 * 1024 * 2;
    bf16_t* g1    = (bf16_t*)p; p += (size_t)4096 * 4096 * 2;
    bf16_t* opart = (bf16_t*)p; p += (size_t)4 * 4096 * 1024 * 2;
    float*  lbuf  = (float*)p;  p += (size_t)4 * 4096 * 16 * 4;

    transpose_all<<<12288, dim3(32, 8), 0, stream>>>(Wqkv, Wo, W1, W2,
                                                     WqkvT, WoT, W1T, W2T);

    ln_bf16<<<4096, 256, 0, stream>>>(x, ln1g, ln1b, xn);
    gemm256<2><<<dim3(12, 16), 512, 0, stream>>>(xn, WqkvT, bqkv,
                                                 qkv, vtb, 4096, 3072, 1024);
    attn_fwd<<<dim3(16, 64), 512, 0, stream>>>(qkv, vtb, opart, lbuf);
    attn_combine<<<4096, 256, 0, stream>>>(opart, lbuf, attnb);
    gemm_w2<<<dim3(8, 32), 512, 0, stream>>>(attnb, WoT, bo, x,
                                             x2, 4096, 1024, 512, 1024);
    ln_bf16<<<4096, 256, 0, stream>>>(x2, ln2g, ln2b, hb);
    gemm256<1><<<dim3(16, 16), 512, 0, stream>>>(hb, W1T, b1,
                                                 g1, nullptr, 4096, 4096, 1024);
    gemm_w2<<<dim3(8, 32), 512, 0, stream>>>(g1, W2T, b2, x2,
                                             outp, 4096, 1024, 2048, 4096);
}

// Round 18
// 240.556 us; speedup vs baseline: 1.0732x; 1.0732x over previous
//
#include <hip/hip_runtime.h>
#include <math.h>

typedef __bf16 bf16_t;
typedef __attribute__((ext_vector_type(8))) __bf16 bf16x8;
typedef __attribute__((ext_vector_type(4))) __bf16 bf16x4;
typedef __attribute__((ext_vector_type(4))) float f32x4;
typedef __attribute__((ext_vector_type(16))) float f32x16;
typedef __attribute__((ext_vector_type(4))) unsigned int u32x4;

#define T_LEN 4096
#define C_DIM 1024
#define NH 16
#define HD 64

__device__ __forceinline__ void gload_lds16(const void* g, void* l) {
    __builtin_amdgcn_global_load_lds(
        (__attribute__((address_space(1))) void*)(g),
        (__attribute__((address_space(3))) void*)(l), 16, 0, 0);
}

__device__ __forceinline__ f32x4 mfma16(bf16x8 a, bf16x8 b, f32x4 c) {
    return __builtin_amdgcn_mfma_f32_16x16x32_bf16(a, b, c, 0, 0, 0);
}

__device__ __forceinline__ f32x16 mfma32(bf16x8 a, bf16x8 b, f32x16 c) {
    return __builtin_amdgcn_mfma_f32_32x32x16_bf16(a, b, c, 0, 0, 0);
}

__device__ __forceinline__ float gelu_exact(float v) {
    return 0.5f * v * (1.0f + erff(v * 0.7071067811865476f));
}

// T12: build two PV B-fragments from 16 P values held in C/D layout.
__device__ __forceinline__ void make_frags2(const f32x16 s, bf16x8& fx, bf16x8& fy) {
    unsigned a0, a1, b0, b1;
    asm("v_cvt_pk_bf16_f32 %0, %1, %2" : "=v"(a0) : "v"(s[0]), "v"(s[1]));
    asm("v_cvt_pk_bf16_f32 %0, %1, %2" : "=v"(a1) : "v"(s[2]), "v"(s[3]));
    asm("v_cvt_pk_bf16_f32 %0, %1, %2" : "=v"(b0) : "v"(s[4]), "v"(s[5]));
    asm("v_cvt_pk_bf16_f32 %0, %1, %2" : "=v"(b1) : "v"(s[6]), "v"(s[7]));
    asm("v_permlane32_swap_b32 %0, %1" : "+v"(a0), "+v"(b0));
    asm("v_permlane32_swap_b32 %0, %1" : "+v"(a1), "+v"(b1));
    u32x4 wa = {a0, a1, b0, b1};
    fx = __builtin_bit_cast(bf16x8, wa);
    unsigned c0, c1, d0, d1;
    asm("v_cvt_pk_bf16_f32 %0, %1, %2" : "=v"(c0) : "v"(s[8]), "v"(s[9]));
    asm("v_cvt_pk_bf16_f32 %0, %1, %2" : "=v"(c1) : "v"(s[10]), "v"(s[11]));
    asm("v_cvt_pk_bf16_f32 %0, %1, %2" : "=v"(d0) : "v"(s[12]), "v"(s[13]));
    asm("v_cvt_pk_bf16_f32 %0, %1, %2" : "=v"(d1) : "v"(s[14]), "v"(s[15]));
    asm("v_permlane32_swap_b32 %0, %1" : "+v"(c0), "+v"(d0));
    asm("v_permlane32_swap_b32 %0, %1" : "+v"(c1), "+v"(d1));
    u32x4 wb = {c0, c1, d0, d1};
    fy = __builtin_bit_cast(bf16x8, wb);
}

// ---------------- merged weight transpose+convert (all 4 weights, 1 launch)
__global__ __launch_bounds__(256) void transpose_all(
    const float* __restrict__ wqkv, const float* __restrict__ wo,
    const float* __restrict__ w1, const float* __restrict__ w2,
    bf16_t* __restrict__ oqkv, bf16_t* __restrict__ owo,
    bf16_t* __restrict__ ow1, bf16_t* __restrict__ ow2)
{
    __shared__ float tile[32][33];
    int s = blockIdx.x;
    const float* in; bf16_t* out; int R, C, NBX;
    if (s < 3072)      {            in = wqkv; out = oqkv; R = 1024; C = 3072; NBX = 96; }
    else if (s < 4096) { s -= 3072; in = wo;   out = owo;  R = 1024; C = 1024; NBX = 32; }
    else if (s < 8192) { s -= 4096; in = w1;   out = ow1;  R = 1024; C = 4096; NBX = 128; }
    else               { s -= 8192; in = w2;   out = ow2;  R = 4096; C = 1024; NBX = 32; }
    const int tx = threadIdx.x, ty = threadIdx.y;
    const int c0 = (s % NBX) * 32, r0 = (s / NBX) * 32;
#pragma unroll
    for (int j = 0; j < 4; ++j)
        tile[ty + j * 8][tx] = in[(size_t)(r0 + ty + j * 8) * C + c0 + tx];
    __syncthreads();
#pragma unroll
    for (int j = 0; j < 4; ++j)
        out[(size_t)(c0 + ty + j * 8) * R + r0 + tx] = (bf16_t)tile[tx][ty + j * 8];
}

// ---------------- LayerNorm fp32 -> bf16
__global__ __launch_bounds__(256) void ln_bf16(
    const float* __restrict__ x, const float* __restrict__ gam,
    const float* __restrict__ bet, bf16_t* __restrict__ out)
{
    const int row = blockIdx.x, t = threadIdx.x;
    const float4 v = *(const float4*)(x + (size_t)row * 1024 + t * 4);
    float s1 = v.x + v.y + v.z + v.w;
    float s2 = v.x * v.x + v.y * v.y + v.z * v.z + v.w * v.w;
#pragma unroll
    for (int m = 1; m < 64; m <<= 1) {
        s1 += __shfl_xor(s1, m);
        s2 += __shfl_xor(s2, m);
    }
    __shared__ float red[8];
    if ((t & 63) == 0) { red[(t >> 6) * 2] = s1; red[(t >> 6) * 2 + 1] = s2; }
    __syncthreads();
    s1 = red[0] + red[2] + red[4] + red[6];
    s2 = red[1] + red[3] + red[5] + red[7];
    const float mu = s1 * (1.0f / 1024.0f);
    const float inv = rsqrtf(s2 * (1.0f / 1024.0f) - mu * mu + 1e-5f);
    const float4 gg = *(const float4*)(gam + t * 4);
    const float4 bb = *(const float4*)(bet + t * 4);
    bf16x4 o;
    o[0] = (bf16_t)((v.x - mu) * inv * gg.x + bb.x);
    o[1] = (bf16_t)((v.y - mu) * inv * gg.y + bb.y);
    o[2] = (bf16_t)((v.z - mu) * inv * gg.z + bb.z);
    o[3] = (bf16_t)((v.w - mu) * inv * gg.w + bb.w);
    *(bf16x4*)(out + (size_t)row * 1024 + t * 4) = o;
}

// ---------------- IN-BLOCK split-K 128x128 GEMM (512 thr = 2 groups of 4 waves)
// Used for Wo (Khalf=512, Kstr=1024) and W2 (Khalf=2048, Kstr=4096).
__global__ __launch_bounds__(512, 1) void gemm_w2(
    const bf16_t* __restrict__ A, const bf16_t* __restrict__ Bt,
    const float* __restrict__ bias, const float* __restrict__ res,
    float* __restrict__ out, int M, int N, int Khalf, int Kstr)
{
    __shared__ alignas(1024) char smem[131072];
    bf16_t* ring = (bf16_t*)smem;
    const int t = threadIdx.x;
    const int grp = t >> 8, tl = t & 255;
    const int lane = tl & 63, w = tl >> 6;
    const int wr = w >> 1, wc = w & 1;
    const int g = lane >> 4, ci = lane & 15;

    const int NB = gridDim.x, MB = gridDim.y;
    const int flat = blockIdx.x + NB * blockIdx.y;
    const int xcd = flat & 7, slot = flat >> 3;
    const int by = xcd * (MB >> 3) + slot / NB;
    const int bx = slot % NB;
    const int m0 = by * 128, n0 = bx * 128;

    const bf16_t* Ag = A + (size_t)grp * Khalf;
    const bf16_t* Bg = Bt + (size_t)grp * Khalf;

    f32x4 acc[4][4];
#pragma unroll
    for (int i = 0; i < 4; ++i)
#pragma unroll
        for (int j = 0; j < 4; ++j)
#pragma unroll
            for (int k = 0; k < 4; ++k) acc[i][j][k] = 0.0f;

    const int r0 = tl >> 2;
    const int cc = (tl & 3) * 8;
    const int nkt = Khalf >> 5;

    auto stage = [&](int kt) {
        const int b = kt & 3;
        const int kk = kt * 32;
        bf16_t* base = ring + grp * 32768 + b * 8192;   // A at base, B at +4096
        char* aB = (char*)base + w * 1024;
        char* bB = (char*)(base + 4096) + w * 1024;
        gload_lds16(Ag + (size_t)(m0 + r0) * Kstr + kk + cc, aB);
        gload_lds16(Ag + (size_t)(m0 + r0 + 64) * Kstr + kk + cc, aB + 4096);
        gload_lds16(Bg + (size_t)(n0 + r0) * Kstr + kk + cc, bB);
        gload_lds16(Bg + (size_t)(n0 + r0 + 64) * Kstr + kk + cc, bB + 4096);
    };

    stage(0);
    stage(1);
    for (int kt = 0; kt < nkt; ++kt) {
        if (kt + 2 < nkt) {
            stage(kt + 2);
            asm volatile("s_waitcnt vmcnt(8)" ::: "memory");
        } else if (kt + 1 < nkt) {
            asm volatile("s_waitcnt vmcnt(4)" ::: "memory");
        } else {
            asm volatile("s_waitcnt vmcnt(0)" ::: "memory");
        }
        __builtin_amdgcn_s_barrier();
        __builtin_amdgcn_sched_barrier(0);
        const bf16_t* base = ring + grp * 32768 + (kt & 3) * 8192;
        const bf16_t* ap = base + (wr * 64 + ci) * 32 + g * 8;
        const bf16_t* bp = base + 4096 + (wc * 64 + ci) * 32 + g * 8;
        bf16x8 af[4], bf[4];
#pragma unroll
        for (int mt = 0; mt < 4; ++mt) af[mt] = *(const bf16x8*)(ap + mt * 16 * 32);
#pragma unroll
        for (int nt = 0; nt < 4; ++nt) bf[nt] = *(const bf16x8*)(bp + nt * 16 * 32);
        __builtin_amdgcn_s_setprio(1);
#pragma unroll
        for (int mt = 0; mt < 4; ++mt)
#pragma unroll
            for (int nt = 0; nt < 4; ++nt)
                acc[mt][nt] = mfma16(af[mt], bf[nt], acc[mt][nt]);
        __builtin_amdgcn_s_setprio(0);
    }

    // cross-group reduction through (now-dead) ring LDS
    __syncthreads();
    float* ex = (float*)smem;
    if (grp == 1) {
#pragma unroll
        for (int mt = 0; mt < 4; ++mt)
#pragma unroll
            for (int nt = 0; nt < 4; ++nt)
                *(f32x4*)(ex + tl * 68 + (mt * 4 + nt) * 4) = acc[mt][nt];
    }
    __syncthreads();
    if (grp == 0) {
#pragma unroll
        for (int nt = 0; nt < 4; ++nt) {
            const int col = n0 + wc * 64 + nt * 16 + ci;
            const float bv = bias[col];
#pragma unroll
            for (int mt = 0; mt < 4; ++mt) {
                const int row = m0 + wr * 64 + mt * 16 + g * 4;
                const f32x4 p1 = *(const f32x4*)(ex + tl * 68 + (mt * 4 + nt) * 4);
#pragma unroll
                for (int r = 0; r < 4; ++r) {
                    out[(size_t)(row + r) * N + col] =
                        acc[mt][nt][r] + p1[r] + bv +
                        res[(size_t)(row + r) * N + col];
                }
            }
        }
    }
}

// ---------------- 256x256 8-phase GEMM (m201: T2+T3+T4+T5) + T1 XCD swizzle
// EPI: 0 = bf16 out, 1 = gelu->bf16,
//      2 = qkv mode: cols <1024 (Q) scaled by C1; K plain; V transposed out.
template <int EPI>
__global__ __launch_bounds__(512, 2) void gemm256(
    const bf16_t* __restrict__ A, const bf16_t* __restrict__ Bt,
    const float* __restrict__ bias, bf16_t* __restrict__ outb,
    bf16_t* __restrict__ vtout, int M, int N, int K)
{
    __shared__ alignas(1024) bf16_t lds[2][2][256 * 64];
    const int t = threadIdx.x, lane = t & 63, w = t >> 6;
    const int g = lane >> 4, ci = lane & 15;
    const int wr = w >> 2, wc = w & 3;
    const int NB = gridDim.x;
    const int nwg = NB * gridDim.y;
    const int flat = blockIdx.x + NB * blockIdx.y;
    const int rix = (flat & 7) * (nwg >> 3) + (flat >> 3);
    const int m0 = (rix / NB) * 256, n0 = (rix % NB) * 256;
    const int NKT = K >> 6;

    f32x4 acc[8][4];
#pragma unroll
    for (int i = 0; i < 8; ++i)
#pragma unroll
        for (int j = 0; j < 4; ++j)
#pragma unroll
            for (int k2 = 0; k2 < 4; ++k2) acc[i][j][k2] = 0.0f;

    const int sw0 = (g ^ (ci & 7)) * 8;
    const int sw1 = ((4 + g) ^ (ci & 7)) * 8;

    auto stage = [&](int h, int ktile, int b) {
#pragma unroll
        for (int i = 0; i < 2; ++i) {
            const int idx = i * 512 + t;
            const int r = idx >> 3;
            const int c = (t & 7) ^ (r & 7);
            const bf16_t* src = ((h < 2) ? A : Bt)
                + (size_t)(((h < 2) ? m0 : n0) + (h & 1) * 128 + r) * K
                + ktile * 64 + c * 8;
            bf16_t* dst = &lds[b][h >> 1][(h & 1) * 8192] + (i * 512 + w * 64) * 8;
            gload_lds16(src, dst);
        }
    };

    bf16x8 a[4][2], b2[2][2][2];

    stage(0, 0, 0); stage(3, 0, 0); stage(1, 0, 0); stage(2, 0, 0);
    if (NKT > 1) { stage(0, 1, 1); stage(3, 1, 1); stage(1, 1, 1); }
    asm volatile("s_waitcnt vmcnt(6)" ::: "memory");
    __builtin_amdgcn_s_barrier();

    for (int kt = 0; kt < NKT; ++kt) {
        const int cur = kt & 1;
        const bf16_t* Ab = &lds[cur][0][0];
        const bf16_t* Bb = &lds[cur][1][0];

#pragma unroll
        for (int mi = 0; mi < 4; ++mi) {
            const bf16_t* ap = Ab + (wr * 64 + mi * 16 + ci) * 64;
            a[mi][0] = *(const bf16x8*)(ap + sw0);
            a[mi][1] = *(const bf16x8*)(ap + sw1);
        }
#pragma unroll
        for (int ni = 0; ni < 2; ++ni) {
            const bf16_t* bp = Bb + (wc * 32 + ni * 16 + ci) * 64;
            b2[0][ni][0] = *(const bf16x8*)(bp + sw0);
            b2[0][ni][1] = *(const bf16x8*)(bp + sw1);
        }
        if (kt + 1 < NKT) stage(2, kt + 1, cur ^ 1);
        __builtin_amdgcn_s_barrier();
        asm volatile("s_waitcnt lgkmcnt(0)" ::: "memory");
        __builtin_amdgcn_sched_barrier(0);
        __builtin_amdgcn_s_setprio(1);
#pragma unroll
        for (int mi = 0; mi < 4; ++mi)
#pragma unroll
            for (int ni = 0; ni < 2; ++ni) {
                acc[mi][ni] = mfma16(a[mi][0], b2[0][ni][0], acc[mi][ni]);
                acc[mi][ni] = mfma16(a[mi][1], b2[0][ni][1], acc[mi][ni]);
            }
        __builtin_amdgcn_s_setprio(0);
        __builtin_amdgcn_s_barrier();

#pragma unroll
        for (int ni = 0; ni < 2; ++ni) {
            const bf16_t* bp = Bb + (128 + wc * 32 + ni * 16 + ci) * 64;
            b2[1][ni][0] = *(const bf16x8*)(bp + sw0);
            b2[1][ni][1] = *(const bf16x8*)(bp + sw1);
        }
        if (kt + 2 < NKT) stage(0, kt + 2, cur);
        __builtin_amdgcn_s_barrier();
        asm volatile("s_waitcnt lgkmcnt(0)" ::: "memory");
        __builtin_amdgcn_sched_barrier(0);
        __builtin_amdgcn_s_setprio(1);
#pragma unroll
        for (int mi = 0; mi < 4; ++mi)
#pragma unroll
            for (int ni = 0; ni < 2; ++ni) {
                acc[mi][2 + ni] = mfma16(a[mi][0], b2[1][ni][0], acc[mi][2 + ni]);
                acc[mi][2 + ni] = mfma16(a[mi][1], b2[1][ni][1], acc[mi][2 + ni]);
            }
        __builtin_amdgcn_s_setprio(0);
        __builtin_amdgcn_s_barrier();

#pragma unroll
        for (int mi = 0; mi < 4; ++mi) {
            const bf16_t* ap = Ab + (128 + wr * 64 + mi * 16 + ci) * 64;
            a[mi][0] = *(const bf16x8*)(ap + sw0);
            a[mi][1] = *(const bf16x8*)(ap + sw1);
        }
        if (kt + 2 < NKT) stage(3, kt + 2, cur);
        __builtin_amdgcn_s_barrier();
        asm volatile("s_waitcnt lgkmcnt(0)" ::: "memory");
        __builtin_amdgcn_sched_barrier(0);
        __builtin_amdgcn_s_setprio(1);
#pragma unroll
        for (int mi = 0; mi < 4; ++mi)
#pragma unroll
            for (int ni = 0; ni < 2; ++ni) {
                acc[4 + mi][2 + ni] = mfma16(a[mi][0], b2[1][ni][0], acc[4 + mi][2 + ni]);
                acc[4 + mi][2 + ni] = mfma16(a[mi][1], b2[1][ni][1], acc[4 + mi][2 + ni]);
            }
        __builtin_amdgcn_s_setprio(0);
        __builtin_amdgcn_s_barrier();

        if (kt + 2 < NKT) stage(1, kt + 2, cur);
        __builtin_amdgcn_s_barrier();
        __builtin_amdgcn_s_setprio(1);
#pragma unroll
        for (int mi = 0; mi < 4; ++mi)
#pragma unroll
            for (int ni = 0; ni < 2; ++ni) {
                acc[4 + mi][ni] = mfma16(a[mi][0], b2[0][ni][0], acc[4 + mi][ni]);
                acc[4 + mi][ni] = mfma16(a[mi][1], b2[0][ni][1], acc[4 + mi][ni]);
            }
        __builtin_amdgcn_s_setprio(0);
        if (kt + 2 < NKT) asm volatile("s_waitcnt vmcnt(6)" ::: "memory");
        else              asm volatile("s_waitcnt vmcnt(0)" ::: "memory");
        __builtin_amdgcn_s_barrier();
    }

    const float QSC = 0.125f * 1.4426950408889634f;  // C1 folded into Q
#pragma unroll
    for (int mrep = 0; mrep < 8; ++mrep) {
        const int row = m0 + (mrep >> 2) * 128 + wr * 64 + (mrep & 3) * 16 + g * 4;
#pragma unroll
        for (int nrep = 0; nrep < 4; ++nrep) {
            const int col = n0 + (nrep >> 1) * 128 + wc * 32 + (nrep & 1) * 16 + ci;
            const float bv = bias[col];
            if (EPI == 2 && col >= 2048) {
                const int cv = col - 2048;
                bf16x4 o4;
#pragma unroll
                for (int jr = 0; jr < 4; ++jr)
                    o4[jr] = (bf16_t)(acc[mrep][nrep][jr] + bv);
                *(bf16x4*)(vtout + (size_t)(cv >> 6) * 262144
                           + (size_t)(cv & 63) * 4096 + row) = o4;
            } else {
                const float sc = (EPI == 2 && col < 1024) ? QSC : 1.0f;
#pragma unroll
                for (int jr = 0; jr < 4; ++jr) {
                    float v = acc[mrep][nrep][jr] + bv;
                    if constexpr (EPI == 1) v = gelu_exact(v);
                    if (EPI == 2) v *= sc;
                    outb[(size_t)(row + jr) * N + col] = (bf16_t)v;
                }
            }
        }
    }
}

// ---------------- causal flash attention, 2-way split-KV (r16-proven form)
// 4 warps x 32 q = 128 q-rows; KV 64-row tiles double-buffered (32 KB LDS).
// Q pre-scaled by C1 in qkv epilogue; p = exp2(s) raw; shared scale cancels
// in O/l at combine. l via MFMA row-sum; bf16 partials; LPT order.
__global__ __launch_bounds__(256, 2) void attn_fwd(
    const bf16_t* __restrict__ qkv, const bf16_t* __restrict__ vt,
    bf16_t* __restrict__ opart, float* __restrict__ lbuf)
{
    __shared__ alignas(1024) bf16_t Klds[2][64 * 64];
    __shared__ alignas(1024) bf16_t Vlds[2][64 * 64];   // V^T tile [d][kpos]
    const int t = threadIdx.x, lane = t & 63, w = t >> 6;
    const int hi = lane >> 5, li = lane & 31;
    const int lq = li >> 2;
    const int h = blockIdx.x;
    const int y = blockIdx.y;
    const int qt = 31 - (y >> 1);                        // LPT: big tiles first
    const int chunk = y & 1;
    const int q0 = qt * 128;
    const int qrow = q0 + w * 32 + li;
    const int wDiag = 2 * qt + (w >> 1);
    const int ktA = chunk ? (qt + 1) : 0;
    const int ktB = chunk ? (2 * qt + 2) : (qt + 1);

    bf16x8 qf[4];
#pragma unroll
    for (int ks = 0; ks < 4; ++ks)
        qf[ks] = *(const bf16x8*)(qkv + (size_t)qrow * 3072 + h * 64 + ks * 16 + hi * 8);
    bf16x8 ones8;
#pragma unroll
    for (int j = 0; j < 8; ++j) ones8[j] = (bf16_t)1.0f;

    f32x16 oacc[2], lacc;
#pragma unroll
    for (int r = 0; r < 16; ++r) { oacc[0][r] = 0.0f; oacc[1][r] = 0.0f; lacc[r] = 0.0f; }

    const int sr = t >> 3;
    const int sx = ((t & 7) ^ ((sr >> 2) & 7)) * 8;

    auto stageKV = [&](int kt, int b) {
        const size_t kbase = (size_t)(kt * 64) * 3072 + 1024 + h * 64 + sx;
        const size_t vbase = (size_t)h * 262144 + (size_t)kt * 64 + sx;
#pragma unroll
        for (int i = 0; i < 2; ++i) {
            gload_lds16(qkv + kbase + (size_t)(i * 32 + sr) * 3072,
                        (char*)&Klds[b][0] + (size_t)(i * 2048 + t * 8) * 2);
            gload_lds16(vt + vbase + (size_t)(i * 32 + sr) * 4096,
                        (char*)&Vlds[b][0] + (size_t)(i * 2048 + t * 8) * 2);
        }
    };

    stageKV(ktA, 0);
    for (int kt = ktA; kt < ktB; ++kt) {
        const int cur = (kt - ktA) & 1;
        asm volatile("s_waitcnt vmcnt(0)" ::: "memory");
        __syncthreads();
        if (kt + 1 < ktB) stageKV(kt + 1, cur ^ 1);

        if (kt <= wDiag) {
            const bf16_t* Kb = &Klds[cur][0];
            const bf16_t* Vb = &Vlds[cur][0];
            f32x16 s0, s1;
#pragma unroll
            for (int r = 0; r < 16; ++r) { s0[r] = 0.0f; s1[r] = 0.0f; }

            __builtin_amdgcn_s_setprio(1);
#pragma unroll
            for (int ks = 0; ks < 4; ++ks) {
                const int cs = ((ks * 2 + hi) ^ lq) * 8;
                s0 = mfma32(*(const bf16x8*)(Kb + li * 64 + cs), qf[ks], s0);
                s1 = mfma32(*(const bf16x8*)(Kb + (32 + li) * 64 + cs), qf[ks], s1);
            }
            __builtin_amdgcn_s_setprio(0);

            bf16x8 vf[4][2];
#pragma unroll
            for (int ks = 0; ks < 4; ++ks) {
                const int cs = ((ks * 2 + hi) ^ lq) * 8;
                vf[ks][0] = *(const bf16x8*)(Vb + li * 64 + cs);
                vf[ks][1] = *(const bf16x8*)(Vb + (32 + li) * 64 + cs);
            }

            if (kt == wDiag) {
                const int kb0 = kt * 64 + 4 * hi;
#pragma unroll
                for (int r = 0; r < 16; ++r) {
                    const int kp0 = kb0 + (r & 3) + 8 * (r >> 2);
                    if (kp0 > qrow) s0[r] = -1e30f;
                    if (kp0 + 32 > qrow) s1[r] = -1e30f;
                }
            }
#pragma unroll
            for (int r = 0; r < 16; ++r) {
                s0[r] = exp2f(s0[r]);
                s1[r] = exp2f(s1[r]);
            }

            bf16x8 pf[4];
            make_frags2(s0, pf[0], pf[1]);
            make_frags2(s1, pf[2], pf[3]);

            __builtin_amdgcn_s_setprio(1);
#pragma unroll
            for (int ks = 0; ks < 4; ++ks) {
                oacc[0] = mfma32(vf[ks][0], pf[ks], oacc[0]);
                oacc[1] = mfma32(vf[ks][1], pf[ks], oacc[1]);
                lacc    = mfma32(ones8,     pf[ks], lacc);
            }
            __builtin_amdgcn_s_setprio(0);
        }
        __syncthreads();
    }

    bf16_t* op = opart + ((size_t)chunk * T_LEN + qrow) * 1024 + h * 64 + hi * 4;
#pragma unroll
    for (int dblk = 0; dblk < 2; ++dblk)
#pragma unroll
        for (int gi = 0; gi < 4; ++gi) {
            bf16x4 o4;
#pragma unroll
            for (int j = 0; j < 4; ++j) o4[j] = (bf16_t)oacc[dblk][gi * 4 + j];
            *(bf16x4*)(op + dblk * 32 + gi * 8) = o4;
        }
    if (hi == 0)
        lbuf[((size_t)chunk * T_LEN + qrow) * NH + h] = lacc[0];
}

// ---------------- 2-way split-KV combine (shared scale cancels in O/l)
__global__ __launch_bounds__(256) void attn_combine(
    const bf16_t* __restrict__ opart, const float* __restrict__ lbuf,
    bf16_t* __restrict__ out)
{
    const int row = blockIdx.x, t = threadIdx.x;
    const int c = t * 4, h = c >> 6;
    const float l0 = lbuf[(size_t)row * NH + h];
    const float l1 = lbuf[((size_t)T_LEN + row) * NH + h];
    const float inv = 1.0f / (l0 + l1);
    const bf16x4 o0 = *(const bf16x4*)(opart + (size_t)row * 1024 + c);
    const bf16x4 o1 = *(const bf16x4*)(opart + ((size_t)T_LEN + row) * 1024 + c);
    bf16x4 o;
#pragma unroll
    for (int j = 0; j < 4; ++j)
        o[j] = (bf16_t)(((float)o0[j] + (float)o1[j]) * inv);
    *(bf16x4*)(out + (size_t)row * 1024 + c) = o;
}

extern "C" void kernel_launch(void* const* d_in, const int* in_sizes, int n_in,
                              void* d_out, int out_size, void* d_ws, size_t ws_size,
                              hipStream_t stream)
{
    const float* x    = (const float*)d_in[0];
    const float* ln1g = (const float*)d_in[1];
    const float* ln1b = (const float*)d_in[2];
    const float* Wqkv = (const float*)d_in[3];
    const float* bqkv = (const float*)d_in[4];
    const float* Wo   = (const float*)d_in[5];
    const float* bo   = (const float*)d_in[6];
    const float* ln2g = (const float*)d_in[7];
    const float* ln2b = (const float*)d_in[8];
    const float* W1   = (const float*)d_in[9];
    const float* b1   = (const float*)d_in[10];
    const float* W2   = (const float*)d_in[11];
    const float* b2   = (const float*)d_in[12];
    float* outp = (float*)d_out;

    char* p = (char*)d_ws;
    bf16_t* WqkvT = (bf16_t*)p; p += (size_t)3072 * 1024 * 2;
    bf16_t* WoT   = (bf16_t*)p; p += (size_t)1024 * 1024 * 2;
    bf16_t* W1T   = (bf16_t*)p; p += (size_t)4096 * 1024 * 2;
    bf16_t* W2T   = (bf16_t*)p; p += (size_t)1024 * 4096 * 2;
    bf16_t* xn    = (bf16_t*)p; p += (size_t)4096 * 1024 * 2;
    bf16_t* qkv   = (bf16_t*)p; p += (size_t)4096 * 3072 * 2;
    bf16_t* vtb   = (bf16_t*)p; p += (size_t)16 * 64 * 4096 * 2;
    bf16_t* attnb = (bf16_t*)p; p += (size_t)4096 * 1024 * 2;
    float*  x2    = (float*)p;  p += (size_t)4096 * 1024 * 4;
    bf16_t* hb    = (bf16_t*)p; p += (size_t)4096 * 1024 * 2;
    bf16_t* g1    = (bf16_t*)p; p += (size_t)4096 * 4096 * 2;
    bf16_t* opart = (bf16_t*)p; p += (size_t)2 * 4096 * 1024 * 2;
    float*  lbuf  = (float*)p;  p += (size_t)2 * 4096 * 16 * 4;

    transpose_all<<<12288, dim3(32, 8), 0, stream>>>(Wqkv, Wo, W1, W2,
                                                     WqkvT, WoT, W1T, W2T);

    ln_bf16<<<4096, 256, 0, stream>>>(x, ln1g, ln1b, xn);
    gemm256<2><<<dim3(12, 16), 512, 0, stream>>>(xn, WqkvT, bqkv,
                                                 qkv, vtb, 4096, 3072, 1024);
    attn_fwd<<<dim3(16, 64), 256, 0, stream>>>(qkv, vtb, opart, lbuf);
    attn_combine<<<4096, 256, 0, stream>>>(opart, lbuf, attnb);
    gemm_w2<<<dim3(8, 32), 512, 0, stream>>>(attnb, WoT, bo, x,
                                             x2, 4096, 1024, 512, 1024);
    ln_bf16<<<4096, 256, 0, stream>>>(x2, ln2g, ln2b, hb);
    gemm256<1><<<dim3(16, 16), 512, 0, stream>>>(hb, W1T, b1,
                                                 g1, nullptr, 4096, 4096, 1024);
    gemm_w2<<<dim3(8, 32), 512, 0, stream>>>(g1, W2T, b2, x2,
                                             outp, 4096, 1024, 2048, 4096);
}

// Round 19
// 239.001 us; speedup vs baseline: 1.0802x; 1.0065x over previous
//
#include <hip/hip_runtime.h>
#include <math.h>

typedef __bf16 bf16_t;
typedef __attribute__((ext_vector_type(8))) __bf16 bf16x8;
typedef __attribute__((ext_vector_type(4))) __bf16 bf16x4;
typedef __attribute__((ext_vector_type(4))) float f32x4;
typedef __attribute__((ext_vector_type(16))) float f32x16;
typedef __attribute__((ext_vector_type(4))) unsigned int u32x4;

#define T_LEN 4096
#define C_DIM 1024
#define NH 16
#define HD 64

__device__ __forceinline__ void gload_lds16(const void* g, void* l) {
    __builtin_amdgcn_global_load_lds(
        (__attribute__((address_space(1))) void*)(g),
        (__attribute__((address_space(3))) void*)(l), 16, 0, 0);
}

__device__ __forceinline__ f32x4 mfma16(bf16x8 a, bf16x8 b, f32x4 c) {
    return __builtin_amdgcn_mfma_f32_16x16x32_bf16(a, b, c, 0, 0, 0);
}

__device__ __forceinline__ f32x16 mfma32(bf16x8 a, bf16x8 b, f32x16 c) {
    return __builtin_amdgcn_mfma_f32_32x32x16_bf16(a, b, c, 0, 0, 0);
}

__device__ __forceinline__ float gelu_exact(float v) {
    return 0.5f * v * (1.0f + erff(v * 0.7071067811865476f));
}

// T12: build two PV B-fragments from 16 P values held in C/D layout.
__device__ __forceinline__ void make_frags2(const f32x16 s, bf16x8& fx, bf16x8& fy) {
    unsigned a0, a1, b0, b1;
    asm("v_cvt_pk_bf16_f32 %0, %1, %2" : "=v"(a0) : "v"(s[0]), "v"(s[1]));
    asm("v_cvt_pk_bf16_f32 %0, %1, %2" : "=v"(a1) : "v"(s[2]), "v"(s[3]));
    asm("v_cvt_pk_bf16_f32 %0, %1, %2" : "=v"(b0) : "v"(s[4]), "v"(s[5]));
    asm("v_cvt_pk_bf16_f32 %0, %1, %2" : "=v"(b1) : "v"(s[6]), "v"(s[7]));
    asm("v_permlane32_swap_b32 %0, %1" : "+v"(a0), "+v"(b0));
    asm("v_permlane32_swap_b32 %0, %1" : "+v"(a1), "+v"(b1));
    u32x4 wa = {a0, a1, b0, b1};
    fx = __builtin_bit_cast(bf16x8, wa);
    unsigned c0, c1, d0, d1;
    asm("v_cvt_pk_bf16_f32 %0, %1, %2" : "=v"(c0) : "v"(s[8]), "v"(s[9]));
    asm("v_cvt_pk_bf16_f32 %0, %1, %2" : "=v"(c1) : "v"(s[10]), "v"(s[11]));
    asm("v_cvt_pk_bf16_f32 %0, %1, %2" : "=v"(d0) : "v"(s[12]), "v"(s[13]));
    asm("v_cvt_pk_bf16_f32 %0, %1, %2" : "=v"(d1) : "v"(s[14]), "v"(s[15]));
    asm("v_permlane32_swap_b32 %0, %1" : "+v"(c0), "+v"(d0));
    asm("v_permlane32_swap_b32 %0, %1" : "+v"(c1), "+v"(d1));
    u32x4 wb = {c0, c1, d0, d1};
    fy = __builtin_bit_cast(bf16x8, wb);
}

// ---------------- merged preamble: 4 weight transposes + LN1 in ONE launch
// blocks [0,12288): fp32 [R][C] -> bf16 [C][R] transpose tiles;
// blocks [12288,16384): LayerNorm rows of x -> xn (reuses tile LDS as scratch).
__global__ __launch_bounds__(256) void prep_all(
    const float* __restrict__ wqkv, const float* __restrict__ wo,
    const float* __restrict__ w1, const float* __restrict__ w2,
    bf16_t* __restrict__ oqkv, bf16_t* __restrict__ owo,
    bf16_t* __restrict__ ow1, bf16_t* __restrict__ ow2,
    const float* __restrict__ x, const float* __restrict__ gam,
    const float* __restrict__ bet, bf16_t* __restrict__ oxn)
{
    __shared__ float tile[32][33];
    int s = blockIdx.x;
    const int t = threadIdx.x;
    if (s >= 12288) {
        // -------- LayerNorm fp32 -> bf16 (one row per block)
        const int row = s - 12288;
        const float4 v = *(const float4*)(x + (size_t)row * 1024 + t * 4);
        float s1 = v.x + v.y + v.z + v.w;
        float s2 = v.x * v.x + v.y * v.y + v.z * v.z + v.w * v.w;
#pragma unroll
        for (int m = 1; m < 64; m <<= 1) {
            s1 += __shfl_xor(s1, m);
            s2 += __shfl_xor(s2, m);
        }
        float* red = &tile[0][0];
        if ((t & 63) == 0) { red[(t >> 6) * 2] = s1; red[(t >> 6) * 2 + 1] = s2; }
        __syncthreads();
        s1 = red[0] + red[2] + red[4] + red[6];
        s2 = red[1] + red[3] + red[5] + red[7];
        const float mu = s1 * (1.0f / 1024.0f);
        const float inv = rsqrtf(s2 * (1.0f / 1024.0f) - mu * mu + 1e-5f);
        const float4 gg = *(const float4*)(gam + t * 4);
        const float4 bb = *(const float4*)(bet + t * 4);
        bf16x4 o;
        o[0] = (bf16_t)((v.x - mu) * inv * gg.x + bb.x);
        o[1] = (bf16_t)((v.y - mu) * inv * gg.y + bb.y);
        o[2] = (bf16_t)((v.z - mu) * inv * gg.z + bb.z);
        o[3] = (bf16_t)((v.w - mu) * inv * gg.w + bb.w);
        *(bf16x4*)(oxn + (size_t)row * 1024 + t * 4) = o;
        return;
    }
    // -------- weight transpose tile
    const float* in; bf16_t* out; int R, C, NBX;
    if (s < 3072)      {            in = wqkv; out = oqkv; R = 1024; C = 3072; NBX = 96; }
    else if (s < 4096) { s -= 3072; in = wo;   out = owo;  R = 1024; C = 1024; NBX = 32; }
    else if (s < 8192) { s -= 4096; in = w1;   out = ow1;  R = 1024; C = 4096; NBX = 128; }
    else               { s -= 8192; in = w2;   out = ow2;  R = 4096; C = 1024; NBX = 32; }
    const int tx = t & 31, ty = t >> 5;
    const int c0 = (s % NBX) * 32, r0 = (s / NBX) * 32;
#pragma unroll
    for (int j = 0; j < 4; ++j)
        tile[ty + j * 8][tx] = in[(size_t)(r0 + ty + j * 8) * C + c0 + tx];
    __syncthreads();
#pragma unroll
    for (int j = 0; j < 4; ++j)
        out[(size_t)(c0 + ty + j * 8) * R + r0 + tx] = (bf16_t)tile[tx][ty + j * 8];
}

// ---------------- LayerNorm fp32 -> bf16 (still used for LN2)
__global__ __launch_bounds__(256) void ln_bf16(
    const float* __restrict__ x, const float* __restrict__ gam,
    const float* __restrict__ bet, bf16_t* __restrict__ out)
{
    const int row = blockIdx.x, t = threadIdx.x;
    const float4 v = *(const float4*)(x + (size_t)row * 1024 + t * 4);
    float s1 = v.x + v.y + v.z + v.w;
    float s2 = v.x * v.x + v.y * v.y + v.z * v.z + v.w * v.w;
#pragma unroll
    for (int m = 1; m < 64; m <<= 1) {
        s1 += __shfl_xor(s1, m);
        s2 += __shfl_xor(s2, m);
    }
    __shared__ float red[8];
    if ((t & 63) == 0) { red[(t >> 6) * 2] = s1; red[(t >> 6) * 2 + 1] = s2; }
    __syncthreads();
    s1 = red[0] + red[2] + red[4] + red[6];
    s2 = red[1] + red[3] + red[5] + red[7];
    const float mu = s1 * (1.0f / 1024.0f);
    const float inv = rsqrtf(s2 * (1.0f / 1024.0f) - mu * mu + 1e-5f);
    const float4 gg = *(const float4*)(gam + t * 4);
    const float4 bb = *(const float4*)(bet + t * 4);
    bf16x4 o;
    o[0] = (bf16_t)((v.x - mu) * inv * gg.x + bb.x);
    o[1] = (bf16_t)((v.y - mu) * inv * gg.y + bb.y);
    o[2] = (bf16_t)((v.z - mu) * inv * gg.z + bb.z);
    o[3] = (bf16_t)((v.w - mu) * inv * gg.w + bb.w);
    *(bf16x4*)(out + (size_t)row * 1024 + t * 4) = o;
}

// ---------------- IN-BLOCK split-K 128x128 GEMM (512 thr = 2 groups of 4 waves)
// Used for Wo (Khalf=512, Kstr=1024) and W2 (Khalf=2048, Kstr=4096).
// setprio removed: m190 A/B shows setprio is null-to-negative on lockstep
// barrier GEMM structures (only pays in phase-split schedules like gemm256).
__global__ __launch_bounds__(512, 1) void gemm_w2(
    const bf16_t* __restrict__ A, const bf16_t* __restrict__ Bt,
    const float* __restrict__ bias, const float* __restrict__ res,
    float* __restrict__ out, int M, int N, int Khalf, int Kstr)
{
    __shared__ alignas(1024) char smem[131072];
    bf16_t* ring = (bf16_t*)smem;
    const int t = threadIdx.x;
    const int grp = t >> 8, tl = t & 255;
    const int lane = tl & 63, w = tl >> 6;
    const int wr = w >> 1, wc = w & 1;
    const int g = lane >> 4, ci = lane & 15;

    const int NB = gridDim.x, MB = gridDim.y;
    const int flat = blockIdx.x + NB * blockIdx.y;
    const int xcd = flat & 7, slot = flat >> 3;
    const int by = xcd * (MB >> 3) + slot / NB;
    const int bx = slot % NB;
    const int m0 = by * 128, n0 = bx * 128;

    const bf16_t* Ag = A + (size_t)grp * Khalf;
    const bf16_t* Bg = Bt + (size_t)grp * Khalf;

    f32x4 acc[4][4];
#pragma unroll
    for (int i = 0; i < 4; ++i)
#pragma unroll
        for (int j = 0; j < 4; ++j)
#pragma unroll
            for (int k = 0; k < 4; ++k) acc[i][j][k] = 0.0f;

    const int r0 = tl >> 2;
    const int cc = (tl & 3) * 8;
    const int nkt = Khalf >> 5;

    auto stage = [&](int kt) {
        const int b = kt & 3;
        const int kk = kt * 32;
        bf16_t* base = ring + grp * 32768 + b * 8192;   // A at base, B at +4096
        char* aB = (char*)base + w * 1024;
        char* bB = (char*)(base + 4096) + w * 1024;
        gload_lds16(Ag + (size_t)(m0 + r0) * Kstr + kk + cc, aB);
        gload_lds16(Ag + (size_t)(m0 + r0 + 64) * Kstr + kk + cc, aB + 4096);
        gload_lds16(Bg + (size_t)(n0 + r0) * Kstr + kk + cc, bB);
        gload_lds16(Bg + (size_t)(n0 + r0 + 64) * Kstr + kk + cc, bB + 4096);
    };

    stage(0);
    stage(1);
    for (int kt = 0; kt < nkt; ++kt) {
        if (kt + 2 < nkt) {
            stage(kt + 2);
            asm volatile("s_waitcnt vmcnt(8)" ::: "memory");
        } else if (kt + 1 < nkt) {
            asm volatile("s_waitcnt vmcnt(4)" ::: "memory");
        } else {
            asm volatile("s_waitcnt vmcnt(0)" ::: "memory");
        }
        __builtin_amdgcn_s_barrier();
        __builtin_amdgcn_sched_barrier(0);
        const bf16_t* base = ring + grp * 32768 + (kt & 3) * 8192;
        const bf16_t* ap = base + (wr * 64 + ci) * 32 + g * 8;
        const bf16_t* bp = base + 4096 + (wc * 64 + ci) * 32 + g * 8;
        bf16x8 af[4], bf[4];
#pragma unroll
        for (int mt = 0; mt < 4; ++mt) af[mt] = *(const bf16x8*)(ap + mt * 16 * 32);
#pragma unroll
        for (int nt = 0; nt < 4; ++nt) bf[nt] = *(const bf16x8*)(bp + nt * 16 * 32);
#pragma unroll
        for (int mt = 0; mt < 4; ++mt)
#pragma unroll
            for (int nt = 0; nt < 4; ++nt)
                acc[mt][nt] = mfma16(af[mt], bf[nt], acc[mt][nt]);
    }

    // cross-group reduction through (now-dead) ring LDS
    __syncthreads();
    float* ex = (float*)smem;
    if (grp == 1) {
#pragma unroll
        for (int mt = 0; mt < 4; ++mt)
#pragma unroll
            for (int nt = 0; nt < 4; ++nt)
                *(f32x4*)(ex + tl * 68 + (mt * 4 + nt) * 4) = acc[mt][nt];
    }
    __syncthreads();
    if (grp == 0) {
#pragma unroll
        for (int nt = 0; nt < 4; ++nt) {
            const int col = n0 + wc * 64 + nt * 16 + ci;
            const float bv = bias[col];
#pragma unroll
            for (int mt = 0; mt < 4; ++mt) {
                const int row = m0 + wr * 64 + mt * 16 + g * 4;
                const f32x4 p1 = *(const f32x4*)(ex + tl * 68 + (mt * 4 + nt) * 4);
#pragma unroll
                for (int r = 0; r < 4; ++r) {
                    out[(size_t)(row + r) * N + col] =
                        acc[mt][nt][r] + p1[r] + bv +
                        res[(size_t)(row + r) * N + col];
                }
            }
        }
    }
}

// ---------------- 256x256 8-phase GEMM (m201: T2+T3+T4+T5) + T1 XCD swizzle
// EPI: 0 = bf16 out, 1 = gelu->bf16,
//      2 = qkv mode: cols <1024 (Q) scaled by C1; K plain; V transposed out.
template <int EPI>
__global__ __launch_bounds__(512, 2) void gemm256(
    const bf16_t* __restrict__ A, const bf16_t* __restrict__ Bt,
    const float* __restrict__ bias, bf16_t* __restrict__ outb,
    bf16_t* __restrict__ vtout, int M, int N, int K)
{
    __shared__ alignas(1024) bf16_t lds[2][2][256 * 64];
    const int t = threadIdx.x, lane = t & 63, w = t >> 6;
    const int g = lane >> 4, ci = lane & 15;
    const int wr = w >> 2, wc = w & 3;
    const int NB = gridDim.x;
    const int nwg = NB * gridDim.y;
    const int flat = blockIdx.x + NB * blockIdx.y;
    const int rix = (flat & 7) * (nwg >> 3) + (flat >> 3);
    const int m0 = (rix / NB) * 256, n0 = (rix % NB) * 256;
    const int NKT = K >> 6;

    f32x4 acc[8][4];
#pragma unroll
    for (int i = 0; i < 8; ++i)
#pragma unroll
        for (int j = 0; j < 4; ++j)
#pragma unroll
            for (int k2 = 0; k2 < 4; ++k2) acc[i][j][k2] = 0.0f;

    const int sw0 = (g ^ (ci & 7)) * 8;
    const int sw1 = ((4 + g) ^ (ci & 7)) * 8;

    auto stage = [&](int h, int ktile, int b) {
#pragma unroll
        for (int i = 0; i < 2; ++i) {
            const int idx = i * 512 + t;
            const int r = idx >> 3;
            const int c = (t & 7) ^ (r & 7);
            const bf16_t* src = ((h < 2) ? A : Bt)
                + (size_t)(((h < 2) ? m0 : n0) + (h & 1) * 128 + r) * K
                + ktile * 64 + c * 8;
            bf16_t* dst = &lds[b][h >> 1][(h & 1) * 8192] + (i * 512 + w * 64) * 8;
            gload_lds16(src, dst);
        }
    };

    bf16x8 a[4][2], b2[2][2][2];

    stage(0, 0, 0); stage(3, 0, 0); stage(1, 0, 0); stage(2, 0, 0);
    if (NKT > 1) { stage(0, 1, 1); stage(3, 1, 1); stage(1, 1, 1); }
    asm volatile("s_waitcnt vmcnt(6)" ::: "memory");
    __builtin_amdgcn_s_barrier();

    for (int kt = 0; kt < NKT; ++kt) {
        const int cur = kt & 1;
        const bf16_t* Ab = &lds[cur][0][0];
        const bf16_t* Bb = &lds[cur][1][0];

#pragma unroll
        for (int mi = 0; mi < 4; ++mi) {
            const bf16_t* ap = Ab + (wr * 64 + mi * 16 + ci) * 64;
            a[mi][0] = *(const bf16x8*)(ap + sw0);
            a[mi][1] = *(const bf16x8*)(ap + sw1);
        }
#pragma unroll
        for (int ni = 0; ni < 2; ++ni) {
            const bf16_t* bp = Bb + (wc * 32 + ni * 16 + ci) * 64;
            b2[0][ni][0] = *(const bf16x8*)(bp + sw0);
            b2[0][ni][1] = *(const bf16x8*)(bp + sw1);
        }
        if (kt + 1 < NKT) stage(2, kt + 1, cur ^ 1);
        __builtin_amdgcn_s_barrier();
        asm volatile("s_waitcnt lgkmcnt(0)" ::: "memory");
        __builtin_amdgcn_sched_barrier(0);
        __builtin_amdgcn_s_setprio(1);
#pragma unroll
        for (int mi = 0; mi < 4; ++mi)
#pragma unroll
            for (int ni = 0; ni < 2; ++ni) {
                acc[mi][ni] = mfma16(a[mi][0], b2[0][ni][0], acc[mi][ni]);
                acc[mi][ni] = mfma16(a[mi][1], b2[0][ni][1], acc[mi][ni]);
            }
        __builtin_amdgcn_s_setprio(0);
        __builtin_amdgcn_s_barrier();

#pragma unroll
        for (int ni = 0; ni < 2; ++ni) {
            const bf16_t* bp = Bb + (128 + wc * 32 + ni * 16 + ci) * 64;
            b2[1][ni][0] = *(const bf16x8*)(bp + sw0);
            b2[1][ni][1] = *(const bf16x8*)(bp + sw1);
        }
        if (kt + 2 < NKT) stage(0, kt + 2, cur);
        __builtin_amdgcn_s_barrier();
        asm volatile("s_waitcnt lgkmcnt(0)" ::: "memory");
        __builtin_amdgcn_sched_barrier(0);
        __builtin_amdgcn_s_setprio(1);
#pragma unroll
        for (int mi = 0; mi < 4; ++mi)
#pragma unroll
            for (int ni = 0; ni < 2; ++ni) {
                acc[mi][2 + ni] = mfma16(a[mi][0], b2[1][ni][0], acc[mi][2 + ni]);
                acc[mi][2 + ni] = mfma16(a[mi][1], b2[1][ni][1], acc[mi][2 + ni]);
            }
        __builtin_amdgcn_s_setprio(0);
        __builtin_amdgcn_s_barrier();

#pragma unroll
        for (int mi = 0; mi < 4; ++mi) {
            const bf16_t* ap = Ab + (128 + wr * 64 + mi * 16 + ci) * 64;
            a[mi][0] = *(const bf16x8*)(ap + sw0);
            a[mi][1] = *(const bf16x8*)(ap + sw1);
        }
        if (kt + 2 < NKT) stage(3, kt + 2, cur);
        __builtin_amdgcn_s_barrier();
        asm volatile("s_waitcnt lgkmcnt(0)" ::: "memory");
        __builtin_amdgcn_sched_barrier(0);
        __builtin_amdgcn_s_setprio(1);
#pragma unroll
        for (int mi = 0; mi < 4; ++mi)
#pragma unroll
            for (int ni = 0; ni < 2; ++ni) {
                acc[4 + mi][2 + ni] = mfma16(a[mi][0], b2[1][ni][0], acc[4 + mi][2 + ni]);
                acc[4 + mi][2 + ni] = mfma16(a[mi][1], b2[1][ni][1], acc[4 + mi][2 + ni]);
            }
        __builtin_amdgcn_s_setprio(0);
        __builtin_amdgcn_s_barrier();

        if (kt + 2 < NKT) stage(1, kt + 2, cur);
        __builtin_amdgcn_s_barrier();
        __builtin_amdgcn_s_setprio(1);
#pragma unroll
        for (int mi = 0; mi < 4; ++mi)
#pragma unroll
            for (int ni = 0; ni < 2; ++ni) {
                acc[4 + mi][ni] = mfma16(a[mi][0], b2[0][ni][0], acc[4 + mi][ni]);
                acc[4 + mi][ni] = mfma16(a[mi][1], b2[0][ni][1], acc[4 + mi][ni]);
            }
        __builtin_amdgcn_s_setprio(0);
        if (kt + 2 < NKT) asm volatile("s_waitcnt vmcnt(6)" ::: "memory");
        else              asm volatile("s_waitcnt vmcnt(0)" ::: "memory");
        __builtin_amdgcn_s_barrier();
    }

    const float QSC = 0.125f * 1.4426950408889634f;  // C1 folded into Q
#pragma unroll
    for (int mrep = 0; mrep < 8; ++mrep) {
        const int row = m0 + (mrep >> 2) * 128 + wr * 64 + (mrep & 3) * 16 + g * 4;
#pragma unroll
        for (int nrep = 0; nrep < 4; ++nrep) {
            const int col = n0 + (nrep >> 1) * 128 + wc * 32 + (nrep & 1) * 16 + ci;
            const float bv = bias[col];
            if (EPI == 2 && col >= 2048) {
                const int cv = col - 2048;
                bf16x4 o4;
#pragma unroll
                for (int jr = 0; jr < 4; ++jr)
                    o4[jr] = (bf16_t)(acc[mrep][nrep][jr] + bv);
                *(bf16x4*)(vtout + (size_t)(cv >> 6) * 262144
                           + (size_t)(cv & 63) * 4096 + row) = o4;
            } else {
                const float sc = (EPI == 2 && col < 1024) ? QSC : 1.0f;
#pragma unroll
                for (int jr = 0; jr < 4; ++jr) {
                    float v = acc[mrep][nrep][jr] + bv;
                    if constexpr (EPI == 1) v = gelu_exact(v);
                    if (EPI == 2) v *= sc;
                    outb[(size_t)(row + jr) * N + col] = (bf16_t)v;
                }
            }
        }
    }
}

// ---------------- causal flash attention, 2-way split-KV (proven form)
// 4 warps x 32 q = 128 q-rows; KV 64-row tiles double-buffered (32 KB LDS).
// Q pre-scaled by C1 in qkv epilogue; p = exp2(s) raw; shared scale cancels
// in O/l at combine. l via MFMA row-sum; bf16 partials; LPT order.
__global__ __launch_bounds__(256, 2) void attn_fwd(
    const bf16_t* __restrict__ qkv, const bf16_t* __restrict__ vt,
    bf16_t* __restrict__ opart, float* __restrict__ lbuf)
{
    __shared__ alignas(1024) bf16_t Klds[2][64 * 64];
    __shared__ alignas(1024) bf16_t Vlds[2][64 * 64];   // V^T tile [d][kpos]
    const int t = threadIdx.x, lane = t & 63, w = t >> 6;
    const int hi = lane >> 5, li = lane & 31;
    const int lq = li >> 2;
    const int h = blockIdx.x;
    const int y = blockIdx.y;
    const int qt = 31 - (y >> 1);                        // LPT: big tiles first
    const int chunk = y & 1;
    const int q0 = qt * 128;
    const int qrow = q0 + w * 32 + li;
    const int wDiag = 2 * qt + (w >> 1);
    const int ktA = chunk ? (qt + 1) : 0;
    const int ktB = chunk ? (2 * qt + 2) : (qt + 1);

    bf16x8 qf[4];
#pragma unroll
    for (int ks = 0; ks < 4; ++ks)
        qf[ks] = *(const bf16x8*)(qkv + (size_t)qrow * 3072 + h * 64 + ks * 16 + hi * 8);
    bf16x8 ones8;
#pragma unroll
    for (int j = 0; j < 8; ++j) ones8[j] = (bf16_t)1.0f;

    f32x16 oacc[2], lacc;
#pragma unroll
    for (int r = 0; r < 16; ++r) { oacc[0][r] = 0.0f; oacc[1][r] = 0.0f; lacc[r] = 0.0f; }

    const int sr = t >> 3;
    const int sx = ((t & 7) ^ ((sr >> 2) & 7)) * 8;

    auto stageKV = [&](int kt, int b) {
        const size_t kbase = (size_t)(kt * 64) * 3072 + 1024 + h * 64 + sx;
        const size_t vbase = (size_t)h * 262144 + (size_t)kt * 64 + sx;
#pragma unroll
        for (int i = 0; i < 2; ++i) {
            gload_lds16(qkv + kbase + (size_t)(i * 32 + sr) * 3072,
                        (char*)&Klds[b][0] + (size_t)(i * 2048 + t * 8) * 2);
            gload_lds16(vt + vbase + (size_t)(i * 32 + sr) * 4096,
                        (char*)&Vlds[b][0] + (size_t)(i * 2048 + t * 8) * 2);
        }
    };

    stageKV(ktA, 0);
    for (int kt = ktA; kt < ktB; ++kt) {
        const int cur = (kt - ktA) & 1;
        asm volatile("s_waitcnt vmcnt(0)" ::: "memory");
        __syncthreads();
        if (kt + 1 < ktB) stageKV(kt + 1, cur ^ 1);

        if (kt <= wDiag) {
            const bf16_t* Kb = &Klds[cur][0];
            const bf16_t* Vb = &Vlds[cur][0];
            f32x16 s0, s1;
#pragma unroll
            for (int r = 0; r < 16; ++r) { s0[r] = 0.0f; s1[r] = 0.0f; }

            __builtin_amdgcn_s_setprio(1);
#pragma unroll
            for (int ks = 0; ks < 4; ++ks) {
                const int cs = ((ks * 2 + hi) ^ lq) * 8;
                s0 = mfma32(*(const bf16x8*)(Kb + li * 64 + cs), qf[ks], s0);
                s1 = mfma32(*(const bf16x8*)(Kb + (32 + li) * 64 + cs), qf[ks], s1);
            }
            __builtin_amdgcn_s_setprio(0);

            bf16x8 vf[4][2];
#pragma unroll
            for (int ks = 0; ks < 4; ++ks) {
                const int cs = ((ks * 2 + hi) ^ lq) * 8;
                vf[ks][0] = *(const bf16x8*)(Vb + li * 64 + cs);
                vf[ks][1] = *(const bf16x8*)(Vb + (32 + li) * 64 + cs);
            }

            if (kt == wDiag) {
                const int kb0 = kt * 64 + 4 * hi;
#pragma unroll
                for (int r = 0; r < 16; ++r) {
                    const int kp0 = kb0 + (r & 3) + 8 * (r >> 2);
                    if (kp0 > qrow) s0[r] = -1e30f;
                    if (kp0 + 32 > qrow) s1[r] = -1e30f;
                }
            }
#pragma unroll
            for (int r = 0; r < 16; ++r) {
                s0[r] = exp2f(s0[r]);
                s1[r] = exp2f(s1[r]);
            }

            bf16x8 pf[4];
            make_frags2(s0, pf[0], pf[1]);
            make_frags2(s1, pf[2], pf[3]);

            __builtin_amdgcn_s_setprio(1);
#pragma unroll
            for (int ks = 0; ks < 4; ++ks) {
                oacc[0] = mfma32(vf[ks][0], pf[ks], oacc[0]);
                oacc[1] = mfma32(vf[ks][1], pf[ks], oacc[1]);
                lacc    = mfma32(ones8,     pf[ks], lacc);
            }
            __builtin_amdgcn_s_setprio(0);
        }
        __syncthreads();
    }

    bf16_t* op = opart + ((size_t)chunk * T_LEN + qrow) * 1024 + h * 64 + hi * 4;
#pragma unroll
    for (int dblk = 0; dblk < 2; ++dblk)
#pragma unroll
        for (int gi = 0; gi < 4; ++gi) {
            bf16x4 o4;
#pragma unroll
            for (int j = 0; j < 4; ++j) o4[j] = (bf16_t)oacc[dblk][gi * 4 + j];
            *(bf16x4*)(op + dblk * 32 + gi * 8) = o4;
        }
    if (hi == 0)
        lbuf[((size_t)chunk * T_LEN + qrow) * NH + h] = lacc[0];
}

// ---------------- 2-way split-KV combine (shared scale cancels in O/l)
__global__ __launch_bounds__(256) void attn_combine(
    const bf16_t* __restrict__ opart, const float* __restrict__ lbuf,
    bf16_t* __restrict__ out)
{
    const int row = blockIdx.x, t = threadIdx.x;
    const int c = t * 4, h = c >> 6;
    const float l0 = lbuf[(size_t)row * NH + h];
    const float l1 = lbuf[((size_t)T_LEN + row) * NH + h];
    const float inv = 1.0f / (l0 + l1);
    const bf16x4 o0 = *(const bf16x4*)(opart + (size_t)row * 1024 + c);
    const bf16x4 o1 = *(const bf16x4*)(opart + ((size_t)T_LEN + row) * 1024 + c);
    bf16x4 o;
#pragma unroll
    for (int j = 0; j < 4; ++j)
        o[j] = (bf16_t)(((float)o0[j] + (float)o1[j]) * inv);
    *(bf16x4*)(out + (size_t)row * 1024 + c) = o;
}

extern "C" void kernel_launch(void* const* d_in, const int* in_sizes, int n_in,
                              void* d_out, int out_size, void* d_ws, size_t ws_size,
                              hipStream_t stream)
{
    const float* x    = (const float*)d_in[0];
    const float* ln1g = (const float*)d_in[1];
    const float* ln1b = (const float*)d_in[2];
    const float* Wqkv = (const float*)d_in[3];
    const float* bqkv = (const float*)d_in[4];
    const float* Wo   = (const float*)d_in[5];
    const float* bo   = (const float*)d_in[6];
    const float* ln2g = (const float*)d_in[7];
    const float* ln2b = (const float*)d_in[8];
    const float* W1   = (const float*)d_in[9];
    const float* b1   = (const float*)d_in[10];
    const float* W2   = (const float*)d_in[11];
    const float* b2   = (const float*)d_in[12];
    float* outp = (float*)d_out;

    char* p = (char*)d_ws;
    bf16_t* WqkvT = (bf16_t*)p; p += (size_t)3072 * 1024 * 2;
    bf16_t* WoT   = (bf16_t*)p; p += (size_t)1024 * 1024 * 2;
    bf16_t* W1T   = (bf16_t*)p; p += (size_t)4096 * 1024 * 2;
    bf16_t* W2T   = (bf16_t*)p; p += (size_t)1024 * 4096 * 2;
    bf16_t* xn    = (bf16_t*)p; p += (size_t)4096 * 1024 * 2;
    bf16_t* qkv   = (bf16_t*)p; p += (size_t)4096 * 3072 * 2;
    bf16_t* vtb   = (bf16_t*)p; p += (size_t)16 * 64 * 4096 * 2;
    bf16_t* attnb = (bf16_t*)p; p += (size_t)4096 * 1024 * 2;
    float*  x2    = (float*)p;  p += (size_t)4096 * 1024 * 4;
    bf16_t* hb    = (bf16_t*)p; p += (size_t)4096 * 1024 * 2;
    bf16_t* g1    = (bf16_t*)p; p += (size_t)4096 * 4096 * 2;
    bf16_t* opart = (bf16_t*)p; p += (size_t)2 * 4096 * 1024 * 2;
    float*  lbuf  = (float*)p;  p += (size_t)2 * 4096 * 16 * 4;

    prep_all<<<16384, 256, 0, stream>>>(Wqkv, Wo, W1, W2,
                                        WqkvT, WoT, W1T, W2T,
                                        x, ln1g, ln1b, xn);
    gemm256<2><<<dim3(12, 16), 512, 0, stream>>>(xn, WqkvT, bqkv,
                                                 qkv, vtb, 4096, 3072, 1024);
    attn_fwd<<<dim3(16, 64), 256, 0, stream>>>(qkv, vtb, opart, lbuf);
    attn_combine<<<4096, 256, 0, stream>>>(opart, lbuf, attnb);
    gemm_w2<<<dim3(8, 32), 512, 0, stream>>>(attnb, WoT, bo, x,
                                             x2, 4096, 1024, 512, 1024);
    ln_bf16<<<4096, 256, 0, stream>>>(x2, ln2g, ln2b, hb);
    gemm256<1><<<dim3(16, 16), 512, 0, stream>>>(hb, W1T, b1,
                                                 g1, nullptr, 4096, 4096, 1024);
    gemm_w2<<<dim3(8, 32), 512, 0, stream>>>(g1, W2T, b2, x2,
                                             outp, 4096, 1024, 2048, 4096);
}